// Round 1
// baseline (435.004 us; speedup 1.0000x reference)
//
#include <hip/hip_runtime.h>
#include <hip/hip_bf16.h>

#define BB 16
#define LL 2048
#define DD 512
#define BL (BB*LL)
#define TI 32
#define TJ 32
#define RADIUS 15
#define LSTR 520
#define CF 1.25331414f   /* sqrt(2*pi)/2 */

typedef __attribute__((ext_vector_type(8))) short short8_t;
typedef __attribute__((ext_vector_type(4))) float f32x4;

static __device__ __forceinline__ unsigned short f2bf(float x){
  unsigned int u = __float_as_uint(x);
  return (unsigned short)((u + 0x7fffu + ((u >> 16) & 1u)) >> 16);  // RNE
}

// ---- inverse L2 norms for clip_embs rows (one block per row, 128 thr) ----
__global__ void qnorm_kernel(const float* __restrict__ clip, float* __restrict__ invq){
  int row = blockIdx.x;
  const float* p = clip + (size_t)row * DD;
  float4 v = *(const float4*)(p + (threadIdx.x << 2));
  float ss = v.x*v.x + v.y*v.y + v.z*v.z + v.w*v.w;
  for (int m = 32; m; m >>= 1) ss += __shfl_down(ss, m, 64);
  __shared__ float red[2];
  if ((threadIdx.x & 63) == 0) red[threadIdx.x >> 6] = ss;
  __syncthreads();
  if (threadIdx.x == 0)
    invq[row] = 1.0f / fmaxf(sqrtf(red[0] + red[1]), 1e-12f);
}

// ---- valid counts per batch ----
__global__ void mcount_kernel(const int* __restrict__ mask, int* __restrict__ mout){
  int b = blockIdx.x;
  int s = 0;
  for (int j = threadIdx.x; j < LL; j += 256) s += (mask[(size_t)b*LL + j] > 0) ? 1 : 0;
  __shared__ int sred[256];
  sred[threadIdx.x] = s; __syncthreads();
  for (int k = 128; k; k >>= 1){
    if (threadIdx.x < k) sred[threadIdx.x] += sred[threadIdx.x + k];
    __syncthreads();
  }
  if (threadIdx.x == 0) mout[b] = sred[0];
}

// ---- fused main: gram via MFMA, online expsum / logit-sum / band ----
__global__ __launch_bounds__(256) void fused_main(
    const float* __restrict__ embs, const float* __restrict__ clip,
    const float* __restrict__ invq, const int* __restrict__ mcnt,
    float* __restrict__ row_sums)
{
  const int b  = blockIdx.y;
  const int M  = mcnt[b];
  const int i0 = blockIdx.x * TI;
  if (i0 >= M) return;

  __shared__ alignas(16) unsigned short qlds[TJ * LSTR];
  __shared__ float gtab[RADIUS + 1];
  __shared__ float partials[2][TI][3];

  const int tid  = threadIdx.x;
  const int wave = tid >> 6;
  const int lane = tid & 63;
  const int col  = lane & 15;
  const int kg   = lane >> 4;
  const int isub = wave >> 1;
  const int jsub = wave & 1;
  const int iw   = i0 + isub * 16;

  if (tid <= RADIUS)
    gtab[tid] = expm1f(CF * expf(-(float)(tid * tid) * 0.125f));

  // A fragments: rows iw..iw+15, normalization fused (ss over this lane's k-subset,
  // reduced across the 4 k-groups holding the same row via shfl_xor 16/32)
  const int arow = iw + col;              // always < LL
  const float* prow = embs + ((size_t)b * LL + arow) * DD;
  float ss = 0.f;
  for (int kb = 0; kb < 16; ++kb){
    float4 x0 = *(const float4*)(prow + kb * 32 + kg * 8);
    float4 x1 = *(const float4*)(prow + kb * 32 + kg * 8 + 4);
    ss += x0.x*x0.x + x0.y*x0.y + x0.z*x0.z + x0.w*x0.w
        + x1.x*x1.x + x1.y*x1.y + x1.z*x1.z + x1.w*x1.w;
  }
  ss += __shfl_xor(ss, 16, 64);
  ss += __shfl_xor(ss, 32, 64);
  const float sp = 1.0f / fmaxf(sqrtf(ss), 1e-12f);

  short8_t afrag[16];
  for (int kb = 0; kb < 16; ++kb){
    float4 x0 = *(const float4*)(prow + kb * 32 + kg * 8);
    float4 x1 = *(const float4*)(prow + kb * 32 + kg * 8 + 4);
    short8_t f;
    f[0]=(short)f2bf(x0.x*sp); f[1]=(short)f2bf(x0.y*sp);
    f[2]=(short)f2bf(x0.z*sp); f[3]=(short)f2bf(x0.w*sp);
    f[4]=(short)f2bf(x1.x*sp); f[5]=(short)f2bf(x1.y*sp);
    f[6]=(short)f2bf(x1.z*sp); f[7]=(short)f2bf(x1.w*sp);
    afrag[kb] = f;
  }

  float es[4]  = {0,0,0,0};   // sum exp(logit)
  float lsm[4] = {0,0,0,0};   // sum logit
  float bg[4]  = {0,0,0,0};   // sum g_d * logit (band)

  const int nj = (M + TJ - 1) / TJ;
  for (int jt = 0; jt < nj; ++jt){
    const int jb = jt * TJ;
    __syncthreads();
    {   // stage TJ rows of normalized q as bf16 (zeros for j >= M)
      const float* qbase = clip + ((size_t)b * LL + jb) * DD;
      for (int u = 0; u < 16; ++u){
        int f  = u * 256 + tid;
        int r  = f >> 7, c4 = f & 127;
        int j  = jb + r;
        ushort4 wv = make_ushort4(0,0,0,0);
        if (j < M){
          float s = invq[b * LL + j];
          float4 x = *(const float4*)(qbase + ((size_t)r << 9) + (c4 << 2));
          wv = make_ushort4(f2bf(x.x*s), f2bf(x.y*s), f2bf(x.z*s), f2bf(x.w*s));
        }
        *reinterpret_cast<ushort4*>(&qlds[r * LSTR + (c4 << 2)]) = wv;
      }
    }
    __syncthreads();

    const int j0 = jb + jsub * 16;
    f32x4 acc = {0.f, 0.f, 0.f, 0.f};
    const unsigned short* bbase = &qlds[(jsub * 16 + col) * LSTR + kg * 8];
    #pragma unroll
    for (int kb = 0; kb < 16; ++kb){
      short8_t bfrag = *reinterpret_cast<const short8_t*>(bbase + kb * 32);
      acc = __builtin_amdgcn_mfma_f32_16x16x32_bf16(afrag[kb], bfrag, acc, 0, 0, 0);
    }
    const int j = j0 + col;
    if (j < M){
      const int dt = j - iw - kg * 4;
      #pragma unroll
      for (int r = 0; r < 4; ++r){
        float lg = acc[r];           // logits[iw + kg*4 + r][j]
        es[r]  += expf(lg);
        lsm[r] += lg;
        int d = dt - r; int ad = d < 0 ? -d : d;
        if (ad <= RADIUS) bg[r] += gtab[ad] * lg;
      }
    }
  }

  // reduce across the 16 column-lanes of each row group
  #pragma unroll
  for (int m = 1; m < 16; m <<= 1){
    #pragma unroll
    for (int r = 0; r < 4; ++r){
      es[r]  += __shfl_xor(es[r],  m, 64);
      lsm[r] += __shfl_xor(lsm[r], m, 64);
      bg[r]  += __shfl_xor(bg[r],  m, 64);
    }
  }
  if (col == 0){
    #pragma unroll
    for (int r = 0; r < 4; ++r){
      int lrow = isub * 16 + kg * 4 + r;
      partials[jsub][lrow][0] = es[r];
      partials[jsub][lrow][1] = lsm[r];
      partials[jsub][lrow][2] = bg[r];
    }
  }
  __syncthreads();
  if (tid < TI){
    int i = i0 + tid;
    if (i < M){
      float esf = partials[0][tid][0] + partials[1][tid][0];
      float lsf = partials[0][tid][1] + partials[1][tid][1];
      float bgf = partials[0][tid][2] + partials[1][tid][2];
      int dlo = (-RADIUS < -i) ? -i : -RADIUS;
      int dhi = (RADIUS > M - 1 - i) ? (M - 1 - i) : RADIUS;
      float Zt = (float)M, U = 0.f;
      for (int d = dlo; d <= dhi; ++d){
        float uu = CF * expf(-(float)(d * d) * 0.125f);
        float eu = expf(uu);
        Zt += eu - 1.0f;
        U  += uu * eu;
      }
      row_sums[(size_t)b * LL + i] = (U - lsf - bgf) / Zt + logf(esf / Zt);
    }
  }
}

// ---- deterministic final reduce ----
__global__ void finalize_kernel(const float* __restrict__ row_sums,
                                const int* __restrict__ mcnt, float* __restrict__ out){
  __shared__ float red[256];
  float acc = 0.f;
  for (int b = 0; b < BB; ++b){
    int M = mcnt[b];
    float s = 0.f;
    for (int i = threadIdx.x; i < M; i += 256) s += row_sums[(size_t)b * LL + i];
    red[threadIdx.x] = s; __syncthreads();
    for (int k = 128; k; k >>= 1){
      if (threadIdx.x < k) red[threadIdx.x] += red[threadIdx.x + k];
      __syncthreads();
    }
    if (threadIdx.x == 0) acc += red[0] / (float)M;
    __syncthreads();
  }
  if (threadIdx.x == 0) out[0] = acc / (float)BB;
}

extern "C" void kernel_launch(void* const* d_in, const int* in_sizes, int n_in,
                              void* d_out, int out_size, void* d_ws, size_t ws_size,
                              hipStream_t stream) {
  const float* embs = (const float*)d_in[0];
  const float* clip = (const float*)d_in[1];
  const int*   mask = (const int*)d_in[2];
  float* ws   = (float*)d_ws;
  float* invq = ws;                         // BL floats
  int*   mcnt = (int*)(ws + BL);            // 16 ints
  float* rows = ws + BL + 16;               // BL floats
  float* out  = (float*)d_out;

  qnorm_kernel<<<dim3(BL), 128, 0, stream>>>(clip, invq);
  mcount_kernel<<<dim3(BB), 256, 0, stream>>>(mask, mcnt);
  fused_main<<<dim3(LL / TI, BB), 256, 0, stream>>>(embs, clip, invq, mcnt, rows);
  finalize_kernel<<<1, 256, 0, stream>>>(rows, mcnt, out);
}

// Round 2
// 193.038 us; speedup vs baseline: 2.2535x; 2.2535x over previous
//
#include <hip/hip_runtime.h>
#include <hip/hip_bf16.h>

#define BB 16
#define LL 2048
#define DD 512
#define BL (BB*LL)
#define RADIUS 15
#define CF 1.25331414f   /* sqrt(2*pi)/2 */

typedef __attribute__((ext_vector_type(8))) short short8_t;
typedef __attribute__((ext_vector_type(4))) float f32x4;

static __device__ __forceinline__ unsigned short f2bf(float x){
  unsigned int u = __float_as_uint(x);
  return (unsigned short)((u + 0x7fffu + ((u >> 16) & 1u)) >> 16);  // RNE
}

// ============================ fast path ============================

// normalize embs/clip rows -> bf16, one wave per row
__global__ __launch_bounds__(256) void precvt(const float* __restrict__ embs,
                                              const float* __restrict__ clip,
                                              unsigned short* __restrict__ p_bf,
                                              unsigned short* __restrict__ q_bf){
  int gw   = blockIdx.x * 4 + (threadIdx.x >> 6);   // row id in [0, 2*BL)
  int lane = threadIdx.x & 63;
  const float* src; unsigned short* dst;
  if (gw < BL){ src = embs + (size_t)gw * DD;        dst = p_bf + (size_t)gw * DD; }
  else        { src = clip + (size_t)(gw - BL) * DD; dst = q_bf + (size_t)(gw - BL) * DD; }
  float4 x0 = *(const float4*)(src + lane * 8);
  float4 x1 = *(const float4*)(src + lane * 8 + 4);
  float ss = x0.x*x0.x + x0.y*x0.y + x0.z*x0.z + x0.w*x0.w
           + x1.x*x1.x + x1.y*x1.y + x1.z*x1.z + x1.w*x1.w;
  #pragma unroll
  for (int m = 1; m < 64; m <<= 1) ss += __shfl_xor(ss, m, 64);
  float s = 1.0f / fmaxf(sqrtf(ss), 1e-12f);
  short8_t o;
  o[0]=(short)f2bf(x0.x*s); o[1]=(short)f2bf(x0.y*s);
  o[2]=(short)f2bf(x0.z*s); o[3]=(short)f2bf(x0.w*s);
  o[4]=(short)f2bf(x1.x*s); o[5]=(short)f2bf(x1.y*s);
  o[6]=(short)f2bf(x1.z*s); o[7]=(short)f2bf(x1.w*s);
  *(short8_t*)(dst + lane * 8) = o;
}

// valid counts per batch
__global__ void mcount_kernel(const int* __restrict__ mask, int* __restrict__ mout){
  int b = blockIdx.x;
  int s = 0;
  for (int j = threadIdx.x; j < LL; j += 256) s += (mask[(size_t)b*LL + j] > 0) ? 1 : 0;
  __shared__ int sred[256];
  sred[threadIdx.x] = s; __syncthreads();
  for (int k = 128; k; k >>= 1){
    if (threadIdx.x < k) sred[threadIdx.x] += sred[threadIdx.x + k];
    __syncthreads();
  }
  if (threadIdx.x == 0) mout[b] = sred[0];
}

// one independent wave per (16-row i-tile, j-half): no LDS staging, no barriers
__global__ __launch_bounds__(64) void gram_wave(
    const unsigned short* __restrict__ p_bf, const unsigned short* __restrict__ q_bf,
    const int* __restrict__ mcnt, float* __restrict__ part /* [BB][LL][2] float4 */)
{
  const int bid = blockIdx.x;                 // 4096 = 8 xcd * 2 * 256
  const int b   = (bid & 7) * 2 + ((bid >> 3) & 1);   // 2 batches per XCD for L2 locality
  const int idx = bid >> 4;                   // [0,256)
  const int it  = idx & 127;
  const int jh  = idx >> 7;                   // j-half
  const int M   = mcnt[b];
  const int i0  = it * 16;
  if (i0 >= M) return;

  __shared__ float gt[RADIUS + 1];
  const int lane = threadIdx.x;
  const int col  = lane & 15;
  const int kg   = lane >> 4;
  if (lane <= RADIUS)
    gt[lane] = expm1f(CF * __expf(-(float)(lane * lane) * 0.125f));
  __syncthreads();

  // A fragments: 16 rows x 512 k, 64 VGPRs
  const unsigned short* prow = p_bf + ((size_t)(b * LL + i0 + col)) * DD + kg * 8;
  short8_t a[16];
  #pragma unroll
  for (int kb = 0; kb < 16; ++kb) a[kb] = *(const short8_t*)(prow + kb * 32);

  float es[4] = {0,0,0,0}, ls[4] = {0,0,0,0}, bg[4] = {0,0,0,0};
  const int njt = (M + 15) >> 4;
  const unsigned short* qb = q_bf + (size_t)b * LL * DD + (size_t)col * DD + kg * 8;

  for (int jt = jh; jt < njt; jt += 2){
    const int j0 = jt * 16;
    const unsigned short* qrow = qb + (size_t)j0 * DD;
    f32x4 acc = {0.f, 0.f, 0.f, 0.f};
    #pragma unroll
    for (int kb = 0; kb < 16; ++kb){
      short8_t bf = *(const short8_t*)(qrow + kb * 32);
      acc = __builtin_amdgcn_mfma_f32_16x16x32_bf16(a[kb], bf, acc, 0, 0, 0);
    }
    const int j = j0 + col;
    if (j < M){
      const int dt = j - i0 - kg * 4;
      #pragma unroll
      for (int r = 0; r < 4; ++r){
        float lg = acc[r];               // logits[i0 + kg*4 + r][j]
        es[r] += __expf(lg);
        ls[r] += lg;
        int d = dt - r; int ad = d < 0 ? -d : d;
        if (ad <= RADIUS) bg[r] += gt[ad] * lg;
      }
    }
  }

  // reduce across the 16 column lanes
  #pragma unroll
  for (int m = 1; m < 16; m <<= 1){
    #pragma unroll
    for (int r = 0; r < 4; ++r){
      es[r] += __shfl_xor(es[r], m, 64);
      ls[r] += __shfl_xor(ls[r], m, 64);
      bg[r] += __shfl_xor(bg[r], m, 64);
    }
  }
  if (col == 0){
    #pragma unroll
    for (int r = 0; r < 4; ++r){
      int i = i0 + kg * 4 + r;
      float4 v = make_float4(es[r], ls[r], bg[r], 0.f);
      *(float4*)&part[(((size_t)b * LL + i) * 2 + jh) * 4] = v;
    }
  }
}

// per-batch row-sum epilogue with analytic Zt/U prefix tables
__global__ __launch_bounds__(256) void finalize1(const float* __restrict__ part,
                                                 const int* __restrict__ mcnt,
                                                 float* __restrict__ psum){
  const int b = blockIdx.x;
  const int M = mcnt[b];
  __shared__ float e1s[16], tts[16], S1[16], TT[16], red[256];
  const int tid = threadIdx.x;
  if (tid < 16){
    float u  = CF * __expf(-(float)(tid * tid) * 0.125f);
    float eu = __expf(u);
    e1s[tid] = eu - 1.0f;
    tts[tid] = u * eu;
  }
  __syncthreads();
  if (tid == 0){
    float a = 0.f, c = 0.f;
    S1[0] = 0.f; TT[0] = 0.f;
    for (int d = 1; d <= RADIUS; ++d){ a += e1s[d]; c += tts[d]; S1[d] = a; TT[d] = c; }
  }
  __syncthreads();
  const float e10 = e1s[0], tt0 = tts[0];
  float acc = 0.f;
  for (int i = tid; i < M; i += 256){
    float4 h0 = *(const float4*)&part[(((size_t)b * LL + i) * 2 + 0) * 4];
    float4 h1 = *(const float4*)&part[(((size_t)b * LL + i) * 2 + 1) * 4];
    float es = h0.x + h1.x, ls = h0.y + h1.y, bg = h0.z + h1.z;
    int rl = i < RADIUS ? i : RADIUS;
    int rr = (M - 1 - i) < RADIUS ? (M - 1 - i) : RADIUS;
    float Zt = (float)M + e10 + S1[rl] + S1[rr];
    float U  = tt0 + TT[rl] + TT[rr];
    acc += (U - ls - bg) / Zt + logf(es) - logf(Zt);
  }
  red[tid] = acc; __syncthreads();
  for (int k = 128; k; k >>= 1){
    if (tid < k) red[tid] += red[tid + k];
    __syncthreads();
  }
  if (tid == 0) psum[b] = red[0] / (float)M;
}

__global__ void finalize2(const float* __restrict__ psum, float* __restrict__ out){
  if (threadIdx.x == 0){
    float a = 0.f;
    for (int b = 0; b < BB; ++b) a += psum[b];
    out[0] = a / (float)BB;
  }
}

// ======================= fallback path (round-1, known good) =======================
#define TI 32
#define TJ 32
#define LSTR 520

__global__ void fb_qnorm(const float* __restrict__ clip, float* __restrict__ invq){
  int row = blockIdx.x;
  const float* p = clip + (size_t)row * DD;
  float4 v = *(const float4*)(p + (threadIdx.x << 2));
  float ss = v.x*v.x + v.y*v.y + v.z*v.z + v.w*v.w;
  for (int m = 32; m; m >>= 1) ss += __shfl_down(ss, m, 64);
  __shared__ float red[2];
  if ((threadIdx.x & 63) == 0) red[threadIdx.x >> 6] = ss;
  __syncthreads();
  if (threadIdx.x == 0)
    invq[row] = 1.0f / fmaxf(sqrtf(red[0] + red[1]), 1e-12f);
}

__global__ __launch_bounds__(256) void fb_main(
    const float* __restrict__ embs, const float* __restrict__ clip,
    const float* __restrict__ invq, const int* __restrict__ mcnt,
    float* __restrict__ row_sums)
{
  const int b  = blockIdx.y;
  const int M  = mcnt[b];
  const int i0 = blockIdx.x * TI;
  if (i0 >= M) return;
  __shared__ alignas(16) unsigned short qlds[TJ * LSTR];
  __shared__ float gtab[RADIUS + 1];
  __shared__ float partials[2][TI][3];
  const int tid  = threadIdx.x;
  const int wave = tid >> 6;
  const int lane = tid & 63;
  const int col  = lane & 15;
  const int kg   = lane >> 4;
  const int isub = wave >> 1;
  const int jsub = wave & 1;
  const int iw   = i0 + isub * 16;
  if (tid <= RADIUS)
    gtab[tid] = expm1f(CF * expf(-(float)(tid * tid) * 0.125f));
  const int arow = iw + col;
  const float* prow = embs + ((size_t)b * LL + arow) * DD;
  float ss = 0.f;
  for (int kb = 0; kb < 16; ++kb){
    float4 x0 = *(const float4*)(prow + kb * 32 + kg * 8);
    float4 x1 = *(const float4*)(prow + kb * 32 + kg * 8 + 4);
    ss += x0.x*x0.x + x0.y*x0.y + x0.z*x0.z + x0.w*x0.w
        + x1.x*x1.x + x1.y*x1.y + x1.z*x1.z + x1.w*x1.w;
  }
  ss += __shfl_xor(ss, 16, 64);
  ss += __shfl_xor(ss, 32, 64);
  const float sp = 1.0f / fmaxf(sqrtf(ss), 1e-12f);
  short8_t afrag[16];
  for (int kb = 0; kb < 16; ++kb){
    float4 x0 = *(const float4*)(prow + kb * 32 + kg * 8);
    float4 x1 = *(const float4*)(prow + kb * 32 + kg * 8 + 4);
    short8_t f;
    f[0]=(short)f2bf(x0.x*sp); f[1]=(short)f2bf(x0.y*sp);
    f[2]=(short)f2bf(x0.z*sp); f[3]=(short)f2bf(x0.w*sp);
    f[4]=(short)f2bf(x1.x*sp); f[5]=(short)f2bf(x1.y*sp);
    f[6]=(short)f2bf(x1.z*sp); f[7]=(short)f2bf(x1.w*sp);
    afrag[kb] = f;
  }
  float es[4]={0,0,0,0}, lsm[4]={0,0,0,0}, bg[4]={0,0,0,0};
  const int nj = (M + TJ - 1) / TJ;
  for (int jt = 0; jt < nj; ++jt){
    const int jb = jt * TJ;
    __syncthreads();
    {
      const float* qbase = clip + ((size_t)b * LL + jb) * DD;
      for (int u = 0; u < 16; ++u){
        int f  = u * 256 + tid;
        int r  = f >> 7, c4 = f & 127;
        int j  = jb + r;
        ushort4 wv = make_ushort4(0,0,0,0);
        if (j < M){
          float s = invq[b * LL + j];
          float4 x = *(const float4*)(qbase + ((size_t)r << 9) + (c4 << 2));
          wv = make_ushort4(f2bf(x.x*s), f2bf(x.y*s), f2bf(x.z*s), f2bf(x.w*s));
        }
        *reinterpret_cast<ushort4*>(&qlds[r * LSTR + (c4 << 2)]) = wv;
      }
    }
    __syncthreads();
    const int j0 = jb + jsub * 16;
    f32x4 acc = {0.f,0.f,0.f,0.f};
    const unsigned short* bbase = &qlds[(jsub * 16 + col) * LSTR + kg * 8];
    #pragma unroll
    for (int kb = 0; kb < 16; ++kb){
      short8_t bfrag = *reinterpret_cast<const short8_t*>(bbase + kb * 32);
      acc = __builtin_amdgcn_mfma_f32_16x16x32_bf16(afrag[kb], bfrag, acc, 0, 0, 0);
    }
    const int j = j0 + col;
    if (j < M){
      const int dt = j - iw - kg * 4;
      #pragma unroll
      for (int r = 0; r < 4; ++r){
        float lg = acc[r];
        es[r]  += expf(lg);
        lsm[r] += lg;
        int d = dt - r; int ad = d < 0 ? -d : d;
        if (ad <= RADIUS) bg[r] += gtab[ad] * lg;
      }
    }
  }
  #pragma unroll
  for (int m = 1; m < 16; m <<= 1){
    #pragma unroll
    for (int r = 0; r < 4; ++r){
      es[r]  += __shfl_xor(es[r],  m, 64);
      lsm[r] += __shfl_xor(lsm[r], m, 64);
      bg[r]  += __shfl_xor(bg[r],  m, 64);
    }
  }
  if (col == 0){
    #pragma unroll
    for (int r = 0; r < 4; ++r){
      int lrow = isub * 16 + kg * 4 + r;
      partials[jsub][lrow][0] = es[r];
      partials[jsub][lrow][1] = lsm[r];
      partials[jsub][lrow][2] = bg[r];
    }
  }
  __syncthreads();
  if (tid < TI){
    int i = i0 + tid;
    if (i < M){
      float esf = partials[0][tid][0] + partials[1][tid][0];
      float lsf = partials[0][tid][1] + partials[1][tid][1];
      float bgf = partials[0][tid][2] + partials[1][tid][2];
      int dlo = (-RADIUS < -i) ? -i : -RADIUS;
      int dhi = (RADIUS > M - 1 - i) ? (M - 1 - i) : RADIUS;
      float Zt = (float)M, U = 0.f;
      for (int d = dlo; d <= dhi; ++d){
        float uu = CF * expf(-(float)(d * d) * 0.125f);
        float eu = expf(uu);
        Zt += eu - 1.0f;
        U  += uu * eu;
      }
      row_sums[(size_t)b * LL + i] = (U - lsf - bgf) / Zt + logf(esf / Zt);
    }
  }
}

__global__ void fb_finalize(const float* __restrict__ row_sums,
                            const int* __restrict__ mcnt, float* __restrict__ out){
  __shared__ float red[256];
  float acc = 0.f;
  for (int b = 0; b < BB; ++b){
    int M = mcnt[b];
    float s = 0.f;
    for (int i = threadIdx.x; i < M; i += 256) s += row_sums[(size_t)b * LL + i];
    red[threadIdx.x] = s; __syncthreads();
    for (int k = 128; k; k >>= 1){
      if (threadIdx.x < k) red[threadIdx.x] += red[threadIdx.x + k];
      __syncthreads();
    }
    if (threadIdx.x == 0) acc += red[0] / (float)M;
    __syncthreads();
  }
  if (threadIdx.x == 0) out[0] = acc / (float)BB;
}

// ================================ launch ================================

extern "C" void kernel_launch(void* const* d_in, const int* in_sizes, int n_in,
                              void* d_out, int out_size, void* d_ws, size_t ws_size,
                              hipStream_t stream) {
  const float* embs = (const float*)d_in[0];
  const float* clip = (const float*)d_in[1];
  const int*   mask = (const int*)d_in[2];
  float* out = (float*)d_out;

  const size_t REQ = (size_t)2 * BL * DD * sizeof(unsigned short)   // p_bf + q_bf
                   + (size_t)BB * LL * 8 * sizeof(float)            // partials
                   + 64 * sizeof(float);                            // psum + mcnt
  if (ws_size >= REQ){
    unsigned short* p_bf = (unsigned short*)d_ws;
    unsigned short* q_bf = p_bf + (size_t)BL * DD;
    float* part = (float*)(q_bf + (size_t)BL * DD);
    float* psum = part + (size_t)BB * LL * 8;
    int*   mcnt = (int*)(psum + 16);

    precvt<<<dim3(2 * BL / 4), 256, 0, stream>>>(embs, clip, p_bf, q_bf);
    mcount_kernel<<<dim3(BB), 256, 0, stream>>>(mask, mcnt);
    gram_wave<<<dim3(4096), 64, 0, stream>>>(p_bf, q_bf, mcnt, part);
    finalize1<<<dim3(BB), 256, 0, stream>>>(part, mcnt, psum);
    finalize2<<<1, 64, 0, stream>>>(psum, out);
  } else {
    float* ws   = (float*)d_ws;
    float* invq = ws;
    int*   mcnt = (int*)(ws + BL);
    float* rows = ws + BL + 16;
    fb_qnorm<<<dim3(BL), 128, 0, stream>>>(clip, invq);
    mcount_kernel<<<dim3(BB), 256, 0, stream>>>(mask, mcnt);
    fb_main<<<dim3(LL / TI, BB), 256, 0, stream>>>(embs, clip, invq, mcnt, rows);
    fb_finalize<<<1, 256, 0, stream>>>(rows, mcnt, out);
  }
}

// Round 3
// 142.191 us; speedup vs baseline: 3.0593x; 1.3576x over previous
//
#include <hip/hip_runtime.h>
#include <hip/hip_bf16.h>

#define BB 16
#define LL 2048
#define DD 512
#define BL (BB*LL)
#define RADIUS 15
#define CF 1.25331414f   /* sqrt(2*pi)/2 */

typedef __attribute__((ext_vector_type(8))) short short8_t;
typedef __attribute__((ext_vector_type(4))) float f32x4;

static __device__ __forceinline__ unsigned short f2bf(float x){
  unsigned int u = __float_as_uint(x);
  return (unsigned short)((u + 0x7fffu + ((u >> 16) & 1u)) >> 16);  // RNE
}

// ============================ fast path ============================
// p_bf / q_bf fragment-major layout per batch: [kb 0..15][row 0..2047][kg 0..3][8]
// addr(elem8) = b*LL*DD + ((kb*LL + row)*4 + kg)*8      (shorts)

// normalize embs/clip rows -> bf16 fragment-major, one wave per row
__global__ __launch_bounds__(256) void precvt(const float* __restrict__ embs,
                                              const float* __restrict__ clip,
                                              unsigned short* __restrict__ p_bf,
                                              unsigned short* __restrict__ q_bf){
  int gw   = blockIdx.x * 4 + (threadIdx.x >> 6);   // row id in [0, 2*BL)
  int lane = threadIdx.x & 63;
  const float* src; unsigned short* dst; int r;
  if (gw < BL){ src = embs + (size_t)gw * DD;       dst = p_bf + (size_t)(gw >> 11) * LL * DD; r = gw & 2047; }
  else { int g = gw - BL; src = clip + (size_t)g * DD; dst = q_bf + (size_t)(g >> 11) * LL * DD; r = g & 2047; }
  float4 x0 = *(const float4*)(src + lane * 8);
  float4 x1 = *(const float4*)(src + lane * 8 + 4);
  float ss = x0.x*x0.x + x0.y*x0.y + x0.z*x0.z + x0.w*x0.w
           + x1.x*x1.x + x1.y*x1.y + x1.z*x1.z + x1.w*x1.w;
  #pragma unroll
  for (int m = 1; m < 64; m <<= 1) ss += __shfl_xor(ss, m, 64);
  float s = 1.0f / fmaxf(sqrtf(ss), 1e-12f);
  short8_t o;
  o[0]=(short)f2bf(x0.x*s); o[1]=(short)f2bf(x0.y*s);
  o[2]=(short)f2bf(x0.z*s); o[3]=(short)f2bf(x0.w*s);
  o[4]=(short)f2bf(x1.x*s); o[5]=(short)f2bf(x1.y*s);
  o[6]=(short)f2bf(x1.z*s); o[7]=(short)f2bf(x1.w*s);
  // this lane's 8 elems: kb = lane>>2, kg = lane&3
  *(short8_t*)(dst + ((size_t)((lane >> 2) * LL + r) * 4 + (lane & 3)) * 8) = o;
}

// valid counts per batch
__global__ void mcount_kernel(const int* __restrict__ mask, int* __restrict__ mout){
  int b = blockIdx.x;
  int s = 0;
  for (int j = threadIdx.x; j < LL; j += 256) s += (mask[(size_t)b*LL + j] > 0) ? 1 : 0;
  __shared__ int sred[256];
  sred[threadIdx.x] = s; __syncthreads();
  for (int k = 128; k; k >>= 1){
    if (threadIdx.x < k) sred[threadIdx.x] += sred[threadIdx.x + k];
    __syncthreads();
  }
  if (threadIdx.x == 0) mout[b] = sred[0];
}

// one independent wave per (32-row i-tile, j-quarter); 2 A-stripes share each B frag
__global__ __launch_bounds__(64, 2) void gram3(
    const unsigned short* __restrict__ p_bf, const unsigned short* __restrict__ q_bf,
    const int* __restrict__ mcnt, float* __restrict__ part /* [BB][LL][4] float4 */)
{
  const int bid = blockIdx.x;                        // 4096
  const int b   = (bid & 7) * 2 + ((bid >> 3) & 1);  // pin batch -> XCD
  const int idx = bid >> 4;                          // [0,256)
  const int it  = idx & 63;                          // 32-row i-tile
  const int jh  = idx >> 6;                          // j-quarter [0,4)
  const int M   = mcnt[b];
  const int i0  = it * 32;
  if (i0 >= M) return;

  __shared__ float gt[RADIUS + 1];
  const int lane = threadIdx.x;
  const int col  = lane & 15;
  const int kg   = lane >> 4;
  if (lane <= RADIUS)
    gt[lane] = expm1f(CF * __expf(-(float)(lane * lane) * 0.125f));
  __syncthreads();

  const size_t bbase = (size_t)b * LL * DD;

  // A fragments: 2 stripes of 16 rows, 16 kb each (128 VGPRs)
  short8_t a0[16], a1[16];
  #pragma unroll
  for (int kb = 0; kb < 16; ++kb){
    a0[kb] = *(const short8_t*)(p_bf + bbase + ((size_t)(kb * LL + i0      + col) * 4 + kg) * 8);
    a1[kb] = *(const short8_t*)(p_bf + bbase + ((size_t)(kb * LL + i0 + 16 + col) * 4 + kg) * 8);
  }

  float es0[4]={0,0,0,0}, ls0[4]={0,0,0,0}, bg0[4]={0,0,0,0};
  float es1[4]={0,0,0,0}, ls1[4]={0,0,0,0}, bg1[4]={0,0,0,0};
  const int njt = (M + 15) >> 4;

  for (int jt = jh; jt < njt; jt += 4){
    const int j0 = jt * 16;
    f32x4 c0 = {0.f,0.f,0.f,0.f}, c1 = {0.f,0.f,0.f,0.f};
    #pragma unroll
    for (int kb = 0; kb < 16; ++kb){
      short8_t bf = *(const short8_t*)(q_bf + bbase + ((size_t)(kb * LL + j0 + col) * 4 + kg) * 8);
      c0 = __builtin_amdgcn_mfma_f32_16x16x32_bf16(a0[kb], bf, c0, 0, 0, 0);
      c1 = __builtin_amdgcn_mfma_f32_16x16x32_bf16(a1[kb], bf, c1, 0, 0, 0);
    }
    const int j = j0 + col;
    if (j < M){
      const int dt0 = j - i0 - kg * 4;
      #pragma unroll
      for (int r = 0; r < 4; ++r){
        float lg = c0[r];                 // logits[i0 + kg*4 + r][j]
        es0[r] += __expf(lg); ls0[r] += lg;
        int d = dt0 - r; int ad = d < 0 ? -d : d;
        if (ad <= RADIUS) bg0[r] += gt[ad] * lg;
        float lh = c1[r];                 // logits[i0 + 16 + kg*4 + r][j]
        es1[r] += __expf(lh); ls1[r] += lh;
        int d1 = dt0 - 16 - r; int ad1 = d1 < 0 ? -d1 : d1;
        if (ad1 <= RADIUS) bg1[r] += gt[ad1] * lh;
      }
    }
  }

  // reduce across the 16 column lanes
  #pragma unroll
  for (int m = 1; m < 16; m <<= 1){
    #pragma unroll
    for (int r = 0; r < 4; ++r){
      es0[r] += __shfl_xor(es0[r], m, 64); es1[r] += __shfl_xor(es1[r], m, 64);
      ls0[r] += __shfl_xor(ls0[r], m, 64); ls1[r] += __shfl_xor(ls1[r], m, 64);
      bg0[r] += __shfl_xor(bg0[r], m, 64); bg1[r] += __shfl_xor(bg1[r], m, 64);
    }
  }
  if (col == 0){
    #pragma unroll
    for (int r = 0; r < 4; ++r){
      int ia = i0 + kg * 4 + r;
      *(float4*)&part[(((size_t)b * LL + ia) * 4 + jh) * 4] = make_float4(es0[r], ls0[r], bg0[r], 0.f);
      int ib = ia + 16;
      *(float4*)&part[(((size_t)b * LL + ib) * 4 + jh) * 4] = make_float4(es1[r], ls1[r], bg1[r], 0.f);
    }
  }
}

// per-batch row-sum epilogue with analytic Zt/U prefix tables
__global__ __launch_bounds__(256) void finalize1(const float* __restrict__ part,
                                                 const int* __restrict__ mcnt,
                                                 float* __restrict__ psum){
  const int b = blockIdx.x;
  const int M = mcnt[b];
  __shared__ float e1s[16], tts[16], S1[16], TT[16], red[256];
  const int tid = threadIdx.x;
  if (tid < 16){
    float u  = CF * __expf(-(float)(tid * tid) * 0.125f);
    float eu = __expf(u);
    e1s[tid] = eu - 1.0f;
    tts[tid] = u * eu;
  }
  __syncthreads();
  if (tid == 0){
    float a = 0.f, c = 0.f;
    S1[0] = 0.f; TT[0] = 0.f;
    for (int d = 1; d <= RADIUS; ++d){ a += e1s[d]; c += tts[d]; S1[d] = a; TT[d] = c; }
  }
  __syncthreads();
  const float e10 = e1s[0], tt0 = tts[0];
  float acc = 0.f;
  for (int i = tid; i < M; i += 256){
    float es = 0.f, ls = 0.f, bg = 0.f;
    #pragma unroll
    for (int h = 0; h < 4; ++h){
      float4 v = *(const float4*)&part[(((size_t)b * LL + i) * 4 + h) * 4];
      es += v.x; ls += v.y; bg += v.z;
    }
    int rl = i < RADIUS ? i : RADIUS;
    int rr = (M - 1 - i) < RADIUS ? (M - 1 - i) : RADIUS;
    float Zt = (float)M + e10 + S1[rl] + S1[rr];
    float U  = tt0 + TT[rl] + TT[rr];
    acc += (U - ls - bg) / Zt + logf(es) - logf(Zt);
  }
  red[tid] = acc; __syncthreads();
  for (int k = 128; k; k >>= 1){
    if (tid < k) red[tid] += red[tid + k];
    __syncthreads();
  }
  if (tid == 0) psum[b] = red[0] / (float)M;
}

__global__ void finalize2(const float* __restrict__ psum, float* __restrict__ out){
  if (threadIdx.x == 0){
    float a = 0.f;
    for (int b = 0; b < BB; ++b) a += psum[b];
    out[0] = a / (float)BB;
  }
}

// ======================= fallback path (round-1, known good) =======================
#define TI 32
#define TJ 32
#define LSTR 520

__global__ void fb_qnorm(const float* __restrict__ clip, float* __restrict__ invq){
  int row = blockIdx.x;
  const float* p = clip + (size_t)row * DD;
  float4 v = *(const float4*)(p + (threadIdx.x << 2));
  float ss = v.x*v.x + v.y*v.y + v.z*v.z + v.w*v.w;
  for (int m = 32; m; m >>= 1) ss += __shfl_down(ss, m, 64);
  __shared__ float red[2];
  if ((threadIdx.x & 63) == 0) red[threadIdx.x >> 6] = ss;
  __syncthreads();
  if (threadIdx.x == 0)
    invq[row] = 1.0f / fmaxf(sqrtf(red[0] + red[1]), 1e-12f);
}

__global__ __launch_bounds__(256) void fb_main(
    const float* __restrict__ embs, const float* __restrict__ clip,
    const float* __restrict__ invq, const int* __restrict__ mcnt,
    float* __restrict__ row_sums)
{
  const int b  = blockIdx.y;
  const int M  = mcnt[b];
  const int i0 = blockIdx.x * TI;
  if (i0 >= M) return;
  __shared__ alignas(16) unsigned short qlds[TJ * LSTR];
  __shared__ float gtab[RADIUS + 1];
  __shared__ float partials[2][TI][3];
  const int tid  = threadIdx.x;
  const int wave = tid >> 6;
  const int lane = tid & 63;
  const int col  = lane & 15;
  const int kg   = lane >> 4;
  const int isub = wave >> 1;
  const int jsub = wave & 1;
  const int iw   = i0 + isub * 16;
  if (tid <= RADIUS)
    gtab[tid] = expm1f(CF * expf(-(float)(tid * tid) * 0.125f));
  const int arow = iw + col;
  const float* prow = embs + ((size_t)b * LL + arow) * DD;
  float ss = 0.f;
  for (int kb = 0; kb < 16; ++kb){
    float4 x0 = *(const float4*)(prow + kb * 32 + kg * 8);
    float4 x1 = *(const float4*)(prow + kb * 32 + kg * 8 + 4);
    ss += x0.x*x0.x + x0.y*x0.y + x0.z*x0.z + x0.w*x0.w
        + x1.x*x1.x + x1.y*x1.y + x1.z*x1.z + x1.w*x1.w;
  }
  ss += __shfl_xor(ss, 16, 64);
  ss += __shfl_xor(ss, 32, 64);
  const float sp = 1.0f / fmaxf(sqrtf(ss), 1e-12f);
  short8_t afrag[16];
  for (int kb = 0; kb < 16; ++kb){
    float4 x0 = *(const float4*)(prow + kb * 32 + kg * 8);
    float4 x1 = *(const float4*)(prow + kb * 32 + kg * 8 + 4);
    short8_t f;
    f[0]=(short)f2bf(x0.x*sp); f[1]=(short)f2bf(x0.y*sp);
    f[2]=(short)f2bf(x0.z*sp); f[3]=(short)f2bf(x0.w*sp);
    f[4]=(short)f2bf(x1.x*sp); f[5]=(short)f2bf(x1.y*sp);
    f[6]=(short)f2bf(x1.z*sp); f[7]=(short)f2bf(x1.w*sp);
    afrag[kb] = f;
  }
  float es[4]={0,0,0,0}, lsm[4]={0,0,0,0}, bg[4]={0,0,0,0};
  const int nj = (M + TJ - 1) / TJ;
  for (int jt = 0; jt < nj; ++jt){
    const int jb = jt * TJ;
    __syncthreads();
    {
      const float* qbase = clip + ((size_t)b * LL + jb) * DD;
      for (int u = 0; u < 16; ++u){
        int f  = u * 256 + tid;
        int r  = f >> 7, c4 = f & 127;
        int j  = jb + r;
        ushort4 wv = make_ushort4(0,0,0,0);
        if (j < M){
          float s = invq[b * LL + j];
          float4 x = *(const float4*)(qbase + ((size_t)r << 9) + (c4 << 2));
          wv = make_ushort4(f2bf(x.x*s), f2bf(x.y*s), f2bf(x.z*s), f2bf(x.w*s));
        }
        *reinterpret_cast<ushort4*>(&qlds[r * LSTR + (c4 << 2)]) = wv;
      }
    }
    __syncthreads();
    const int j0 = jb + jsub * 16;
    f32x4 acc = {0.f,0.f,0.f,0.f};
    const unsigned short* bbase = &qlds[(jsub * 16 + col) * LSTR + kg * 8];
    #pragma unroll
    for (int kb = 0; kb < 16; ++kb){
      short8_t bfrag = *reinterpret_cast<const short8_t*>(bbase + kb * 32);
      acc = __builtin_amdgcn_mfma_f32_16x16x32_bf16(afrag[kb], bfrag, acc, 0, 0, 0);
    }
    const int j = j0 + col;
    if (j < M){
      const int dt = j - iw - kg * 4;
      #pragma unroll
      for (int r = 0; r < 4; ++r){
        float lg = acc[r];
        es[r]  += expf(lg);
        lsm[r] += lg;
        int d = dt - r; int ad = d < 0 ? -d : d;
        if (ad <= RADIUS) bg[r] += gtab[ad] * lg;
      }
    }
  }
  #pragma unroll
  for (int m = 1; m < 16; m <<= 1){
    #pragma unroll
    for (int r = 0; r < 4; ++r){
      es[r]  += __shfl_xor(es[r],  m, 64);
      lsm[r] += __shfl_xor(lsm[r], m, 64);
      bg[r]  += __shfl_xor(bg[r],  m, 64);
    }
  }
  if (col == 0){
    #pragma unroll
    for (int r = 0; r < 4; ++r){
      int lrow = isub * 16 + kg * 4 + r;
      partials[jsub][lrow][0] = es[r];
      partials[jsub][lrow][1] = lsm[r];
      partials[jsub][lrow][2] = bg[r];
    }
  }
  __syncthreads();
  if (tid < TI){
    int i = i0 + tid;
    if (i < M){
      float esf = partials[0][tid][0] + partials[1][tid][0];
      float lsf = partials[0][tid][1] + partials[1][tid][1];
      float bgf = partials[0][tid][2] + partials[1][tid][2];
      int dlo = (-RADIUS < -i) ? -i : -RADIUS;
      int dhi = (RADIUS > M - 1 - i) ? (M - 1 - i) : RADIUS;
      float Zt = (float)M, U = 0.f;
      for (int d = dlo; d <= dhi; ++d){
        float uu = CF * expf(-(float)(d * d) * 0.125f);
        float eu = expf(uu);
        Zt += eu - 1.0f;
        U  += uu * eu;
      }
      row_sums[(size_t)b * LL + i] = (U - lsf - bgf) / Zt + logf(esf / Zt);
    }
  }
}

__global__ void fb_finalize(const float* __restrict__ row_sums,
                            const int* __restrict__ mcnt, float* __restrict__ out){
  __shared__ float red[256];
  float acc = 0.f;
  for (int b = 0; b < BB; ++b){
    int M = mcnt[b];
    float s = 0.f;
    for (int i = threadIdx.x; i < M; i += 256) s += row_sums[(size_t)b * LL + i];
    red[threadIdx.x] = s; __syncthreads();
    for (int k = 128; k; k >>= 1){
      if (threadIdx.x < k) red[threadIdx.x] += red[threadIdx.x + k];
      __syncthreads();
    }
    if (threadIdx.x == 0) acc += red[0] / (float)M;
    __syncthreads();
  }
  if (threadIdx.x == 0) out[0] = acc / (float)BB;
}

// ================================ launch ================================

extern "C" void kernel_launch(void* const* d_in, const int* in_sizes, int n_in,
                              void* d_out, int out_size, void* d_ws, size_t ws_size,
                              hipStream_t stream) {
  const float* embs = (const float*)d_in[0];
  const float* clip = (const float*)d_in[1];
  const int*   mask = (const int*)d_in[2];
  float* out = (float*)d_out;

  const size_t REQ = (size_t)2 * BL * DD * sizeof(unsigned short)   // p_bf + q_bf
                   + (size_t)BB * LL * 16 * sizeof(float)           // partials (4 quarters)
                   + 64 * sizeof(float);                            // psum + mcnt
  if (ws_size >= REQ){
    unsigned short* p_bf = (unsigned short*)d_ws;
    unsigned short* q_bf = p_bf + (size_t)BL * DD;
    float* part = (float*)(q_bf + (size_t)BL * DD);
    float* psum = part + (size_t)BB * LL * 16;
    int*   mcnt = (int*)(psum + 16);

    precvt<<<dim3(2 * BL / 4), 256, 0, stream>>>(embs, clip, p_bf, q_bf);
    mcount_kernel<<<dim3(BB), 256, 0, stream>>>(mask, mcnt);
    gram3<<<dim3(4096), 64, 0, stream>>>(p_bf, q_bf, mcnt, part);
    finalize1<<<dim3(BB), 256, 0, stream>>>(part, mcnt, psum);
    finalize2<<<1, 64, 0, stream>>>(psum, out);
  } else {
    float* ws   = (float*)d_ws;
    float* invq = ws;
    int*   mcnt = (int*)(ws + BL);
    float* rows = ws + BL + 16;
    fb_qnorm<<<dim3(BL), 128, 0, stream>>>(clip, invq);
    mcount_kernel<<<dim3(BB), 256, 0, stream>>>(mask, mcnt);
    fb_main<<<dim3(LL / TI, BB), 256, 0, stream>>>(embs, clip, invq, mcnt, rows);
    fb_finalize<<<1, 256, 0, stream>>>(rows, mcnt, out);
  }
}

// Round 4
// 79.884 us; speedup vs baseline: 5.4454x; 1.7800x over previous
//
#include <hip/hip_runtime.h>
#include <hip/hip_bf16.h>

#define BB 16
#define LL 2048
#define DD 512
#define BL (BB*LL)
#define RADIUS 15
#define CF 1.25331414f   /* sqrt(2*pi)/2 */

typedef __attribute__((ext_vector_type(8))) short short8_t;
typedef __attribute__((ext_vector_type(4))) float f32x4;

static __device__ __forceinline__ unsigned short f2bf(float x){
  unsigned int u = __float_as_uint(x);
  return (unsigned short)((u + 0x7fffu + ((u >> 16) & 1u)) >> 16);  // RNE
}

static __device__ __forceinline__ void gld_lds16(const void* g, void* l){
  __builtin_amdgcn_global_load_lds(
      (const __attribute__((address_space(1))) unsigned int*)g,
      (__attribute__((address_space(3))) unsigned int*)l, 16, 0, 0);
}

// ============================ fast path ============================
// p_bf / q_bf fragment-major layout per batch: [kb 0..15][row 0..2047][kg 0..3][8]
// short offset = b*LL*DD + ((kb*LL + row)*4 + kg)*8
// => per (kb, 16-row tile) the data is one contiguous 1 KB chunk.

// valid counts per batch (must run BEFORE precvt now)
__global__ void mcount_kernel(const int* __restrict__ mask, int* __restrict__ mout){
  int b = blockIdx.x;
  int s = 0;
  for (int j = threadIdx.x; j < LL; j += 256) s += (mask[(size_t)b*LL + j] > 0) ? 1 : 0;
  __shared__ int sred[256];
  sred[threadIdx.x] = s; __syncthreads();
  for (int k = 128; k; k >>= 1){
    if (threadIdx.x < k) sred[threadIdx.x] += sred[threadIdx.x + k];
    __syncthreads();
  }
  if (threadIdx.x == 0) mout[b] = sred[0];
}

// normalize embs/clip rows -> bf16 fragment-major; skip rows >= ceil(M/128)*128
__global__ __launch_bounds__(256) void precvt(const float* __restrict__ embs,
                                              const float* __restrict__ clip,
                                              const int* __restrict__ mcnt,
                                              unsigned short* __restrict__ p_bf,
                                              unsigned short* __restrict__ q_bf){
  int gw   = blockIdx.x * 4 + (threadIdx.x >> 6);   // row id in [0, 2*BL)
  int lane = threadIdx.x & 63;
  const float* src; unsigned short* dst; int r, b;
  if (gw < BL){ b = gw >> 11; r = gw & 2047; src = embs + (size_t)gw * DD;
                dst = p_bf + (size_t)b * LL * DD; }
  else { int g = gw - BL; b = g >> 11; r = g & 2047; src = clip + (size_t)g * DD;
         dst = q_bf + (size_t)b * LL * DD; }
  const int RND = (mcnt[b] + 127) & ~127;
  if (r >= RND) return;                              // rows never consumed
  float4 x0 = *(const float4*)(src + lane * 8);
  float4 x1 = *(const float4*)(src + lane * 8 + 4);
  float ss = x0.x*x0.x + x0.y*x0.y + x0.z*x0.z + x0.w*x0.w
           + x1.x*x1.x + x1.y*x1.y + x1.z*x1.z + x1.w*x1.w;
  #pragma unroll
  for (int m = 1; m < 64; m <<= 1) ss += __shfl_xor(ss, m, 64);
  float s = 1.0f / fmaxf(sqrtf(ss), 1e-12f);
  short8_t o;
  o[0]=(short)f2bf(x0.x*s); o[1]=(short)f2bf(x0.y*s);
  o[2]=(short)f2bf(x0.z*s); o[3]=(short)f2bf(x0.w*s);
  o[4]=(short)f2bf(x1.x*s); o[5]=(short)f2bf(x1.y*s);
  o[6]=(short)f2bf(x1.z*s); o[7]=(short)f2bf(x1.w*s);
  *(short8_t*)(dst + ((size_t)((lane >> 2) * LL + r) * 4 + (lane & 3)) * 8) = o;
}

// 4-wave block, 128 i-rows; B j-tile staged once to LDS (global_load_lds, dbuf)
__global__ __launch_bounds__(256, 2) void gram4(
    const unsigned short* __restrict__ p_bf, const unsigned short* __restrict__ q_bf,
    const int* __restrict__ mcnt, float* __restrict__ part /* [BB][LL][4] float4 */)
{
  const int bid = blockIdx.x;                 // 1024
  const int xcd = bid & 7;
  const int k   = bid >> 3;                   // 0..127
  const int b   = (xcd << 1) | (k >> 6);      // batch pinned to XCD
  const int m_  = k & 63;
  const int it  = m_ >> 2;                    // 0..15  (128-row i-tile)
  const int js  = m_ & 3;                     // j-slice [0,4)
  const int M   = mcnt[b];
  const int i0  = it << 7;
  if (i0 >= M) return;

  __shared__ unsigned short bsm[2][8192];     // 2 x 16 KB B-tile buffers
  __shared__ float gt[RADIUS + 1];

  const int tid  = threadIdx.x;
  const int wave = tid >> 6;
  const int lane = tid & 63;
  const int col  = lane & 15;
  const int kg   = lane >> 4;
  const int iw   = i0 + (wave << 5);          // this wave's 32-row stripe base

  if (tid <= RADIUS)
    gt[tid] = expm1f(CF * __expf(-(float)(tid * tid) * 0.125f));

  const size_t bbase = (size_t)b * LL * DD;

  // A fragments: 2 stripes x 16 kb (held in regs for the whole kernel)
  short8_t a0[16], a1[16];
  #pragma unroll
  for (int kb = 0; kb < 16; ++kb){
    a0[kb] = *(const short8_t*)(p_bf + bbase + ((size_t)(kb * LL + iw      + col) * 4 + kg) * 8);
    a1[kb] = *(const short8_t*)(p_bf + bbase + ((size_t)(kb * LL + iw + 16 + col) * 4 + kg) * 8);
  }

  float es0[4]={0,0,0,0}, ls0[4]={0,0,0,0}, bg0[4]={0,0,0,0};
  float es1[4]={0,0,0,0}, ls1[4]={0,0,0,0}, bg1[4]={0,0,0,0};

  const int njt = (M + 15) >> 4;
  const char* qbyte = (const char*)(q_bf + bbase);

  #define STAGE(BF, JT) do {                                                   \
    const int _j0 = (JT) << 4;                                                 \
    _Pragma("unroll")                                                          \
    for (int u = 0; u < 4; ++u){                                               \
      const int _kb = (wave << 2) + u;                                         \
      gld_lds16(qbyte + (size_t)(_kb * LL + _j0) * 64 + lane * 16,             \
                (void*)&bsm[BF][_kb * 512]);                                   \
    }                                                                          \
  } while (0)

  int buf = 0;
  STAGE(0, js);
  __syncthreads();                             // drains vmcnt -> tile visible

  for (int jt = js; jt < njt; jt += 4){
    const int nxt = jt + 4;
    if (nxt < njt) STAGE(buf ^ 1, nxt);        // async prefetch next tile

    const int j0 = jt << 4;
    f32x4 c0 = {0.f,0.f,0.f,0.f}, c1 = {0.f,0.f,0.f,0.f};
    const char* lb = (const char*)&bsm[buf][0] + (col * 4 + kg) * 16;
    #pragma unroll
    for (int kb = 0; kb < 16; ++kb){
      short8_t bfrag = *(const short8_t*)(lb + kb * 1024);   // ds_read_b128, broadcast
      c0 = __builtin_amdgcn_mfma_f32_16x16x32_bf16(a0[kb], bfrag, c0, 0, 0, 0);
      c1 = __builtin_amdgcn_mfma_f32_16x16x32_bf16(a1[kb], bfrag, c1, 0, 0, 0);
    }
    const int j = j0 + col;
    if (j < M){
      const int dt0 = j - iw - (kg << 2);
      #pragma unroll
      for (int r = 0; r < 4; ++r){
        float lg = c0[r];                      // logits[iw + kg*4 + r][j]
        es0[r] += __expf(lg); ls0[r] += lg;
        int d = dt0 - r; int ad = d < 0 ? -d : d;
        if (ad <= RADIUS) bg0[r] += gt[ad] * lg;
        float lh = c1[r];                      // logits[iw + 16 + kg*4 + r][j]
        es1[r] += __expf(lh); ls1[r] += lh;
        int d1 = dt0 - 16 - r; int ad1 = d1 < 0 ? -d1 : d1;
        if (ad1 <= RADIUS) bg1[r] += gt[ad1] * lh;
      }
    }
    __syncthreads();                           // end-of-tile: drains prefetch + LDS
    buf ^= 1;
  }
  #undef STAGE

  // reduce across the 16 column lanes
  #pragma unroll
  for (int m = 1; m < 16; m <<= 1){
    #pragma unroll
    for (int r = 0; r < 4; ++r){
      es0[r] += __shfl_xor(es0[r], m, 64); es1[r] += __shfl_xor(es1[r], m, 64);
      ls0[r] += __shfl_xor(ls0[r], m, 64); ls1[r] += __shfl_xor(ls1[r], m, 64);
      bg0[r] += __shfl_xor(bg0[r], m, 64); bg1[r] += __shfl_xor(bg1[r], m, 64);
    }
  }
  if (col == 0){
    #pragma unroll
    for (int r = 0; r < 4; ++r){
      int ia = iw + (kg << 2) + r;
      *(float4*)&part[(((size_t)b * LL + ia) * 4 + js) * 4] = make_float4(es0[r], ls0[r], bg0[r], 0.f);
      int ib = ia + 16;
      *(float4*)&part[(((size_t)b * LL + ib) * 4 + js) * 4] = make_float4(es1[r], ls1[r], bg1[r], 0.f);
    }
  }
}

// per-batch row-sum epilogue with analytic Zt/U prefix tables
__global__ __launch_bounds__(256) void finalize1(const float* __restrict__ part,
                                                 const int* __restrict__ mcnt,
                                                 float* __restrict__ psum){
  const int b = blockIdx.x;
  const int M = mcnt[b];
  __shared__ float e1s[16], tts[16], S1[16], TT[16], red[256];
  const int tid = threadIdx.x;
  if (tid < 16){
    float u  = CF * __expf(-(float)(tid * tid) * 0.125f);
    float eu = __expf(u);
    e1s[tid] = eu - 1.0f;
    tts[tid] = u * eu;
  }
  __syncthreads();
  if (tid == 0){
    float a = 0.f, c = 0.f;
    S1[0] = 0.f; TT[0] = 0.f;
    for (int d = 1; d <= RADIUS; ++d){ a += e1s[d]; c += tts[d]; S1[d] = a; TT[d] = c; }
  }
  __syncthreads();
  const float e10 = e1s[0], tt0 = tts[0];
  float acc = 0.f;
  for (int i = tid; i < M; i += 256){
    float es = 0.f, ls = 0.f, bg = 0.f;
    #pragma unroll
    for (int h = 0; h < 4; ++h){
      float4 v = *(const float4*)&part[(((size_t)b * LL + i) * 4 + h) * 4];
      es += v.x; ls += v.y; bg += v.z;
    }
    int rl = i < RADIUS ? i : RADIUS;
    int rr = (M - 1 - i) < RADIUS ? (M - 1 - i) : RADIUS;
    float Zt = (float)M + e10 + S1[rl] + S1[rr];
    float U  = tt0 + TT[rl] + TT[rr];
    acc += (U - ls - bg) / Zt + logf(es) - logf(Zt);
  }
  red[tid] = acc; __syncthreads();
  for (int k = 128; k; k >>= 1){
    if (tid < k) red[tid] += red[tid + k];
    __syncthreads();
  }
  if (tid == 0) psum[b] = red[0] / (float)M;
}

__global__ void finalize2(const float* __restrict__ psum, float* __restrict__ out){
  if (threadIdx.x == 0){
    float a = 0.f;
    for (int b = 0; b < BB; ++b) a += psum[b];
    out[0] = a / (float)BB;
  }
}

// ======================= fallback path (round-1, known good) =======================
#define TI 32
#define TJ 32
#define LSTR 520

__global__ void fb_qnorm(const float* __restrict__ clip, float* __restrict__ invq){
  int row = blockIdx.x;
  const float* p = clip + (size_t)row * DD;
  float4 v = *(const float4*)(p + (threadIdx.x << 2));
  float ss = v.x*v.x + v.y*v.y + v.z*v.z + v.w*v.w;
  for (int m = 32; m; m >>= 1) ss += __shfl_down(ss, m, 64);
  __shared__ float red[2];
  if ((threadIdx.x & 63) == 0) red[threadIdx.x >> 6] = ss;
  __syncthreads();
  if (threadIdx.x == 0)
    invq[row] = 1.0f / fmaxf(sqrtf(red[0] + red[1]), 1e-12f);
}

__global__ __launch_bounds__(256) void fb_main(
    const float* __restrict__ embs, const float* __restrict__ clip,
    const float* __restrict__ invq, const int* __restrict__ mcnt,
    float* __restrict__ row_sums)
{
  const int b  = blockIdx.y;
  const int M  = mcnt[b];
  const int i0 = blockIdx.x * TI;
  if (i0 >= M) return;
  __shared__ alignas(16) unsigned short qlds[TJ * LSTR];
  __shared__ float gtab[RADIUS + 1];
  __shared__ float partials[2][TI][3];
  const int tid  = threadIdx.x;
  const int wave = tid >> 6;
  const int lane = tid & 63;
  const int col  = lane & 15;
  const int kg   = lane >> 4;
  const int isub = wave >> 1;
  const int jsub = wave & 1;
  const int iw   = i0 + isub * 16;
  if (tid <= RADIUS)
    gtab[tid] = expm1f(CF * expf(-(float)(tid * tid) * 0.125f));
  const int arow = iw + col;
  const float* prow = embs + ((size_t)b * LL + arow) * DD;
  float ss = 0.f;
  for (int kb = 0; kb < 16; ++kb){
    float4 x0 = *(const float4*)(prow + kb * 32 + kg * 8);
    float4 x1 = *(const float4*)(prow + kb * 32 + kg * 8 + 4);
    ss += x0.x*x0.x + x0.y*x0.y + x0.z*x0.z + x0.w*x0.w
        + x1.x*x1.x + x1.y*x1.y + x1.z*x1.z + x1.w*x1.w;
  }
  ss += __shfl_xor(ss, 16, 64);
  ss += __shfl_xor(ss, 32, 64);
  const float sp = 1.0f / fmaxf(sqrtf(ss), 1e-12f);
  short8_t afrag[16];
  for (int kb = 0; kb < 16; ++kb){
    float4 x0 = *(const float4*)(prow + kb * 32 + kg * 8);
    float4 x1 = *(const float4*)(prow + kb * 32 + kg * 8 + 4);
    short8_t f;
    f[0]=(short)f2bf(x0.x*sp); f[1]=(short)f2bf(x0.y*sp);
    f[2]=(short)f2bf(x0.z*sp); f[3]=(short)f2bf(x0.w*sp);
    f[4]=(short)f2bf(x1.x*sp); f[5]=(short)f2bf(x1.y*sp);
    f[6]=(short)f2bf(x1.z*sp); f[7]=(short)f2bf(x1.w*sp);
    afrag[kb] = f;
  }
  float es[4]={0,0,0,0}, lsm[4]={0,0,0,0}, bg[4]={0,0,0,0};
  const int nj = (M + TJ - 1) / TJ;
  for (int jt = 0; jt < nj; ++jt){
    const int jb = jt * TJ;
    __syncthreads();
    {
      const float* qbase = clip + ((size_t)b * LL + jb) * DD;
      for (int u = 0; u < 16; ++u){
        int f  = u * 256 + tid;
        int r  = f >> 7, c4 = f & 127;
        int j  = jb + r;
        ushort4 wv = make_ushort4(0,0,0,0);
        if (j < M){
          float s = invq[b * LL + j];
          float4 x = *(const float4*)(qbase + ((size_t)r << 9) + (c4 << 2));
          wv = make_ushort4(f2bf(x.x*s), f2bf(x.y*s), f2bf(x.z*s), f2bf(x.w*s));
        }
        *reinterpret_cast<ushort4*>(&qlds[r * LSTR + (c4 << 2)]) = wv;
      }
    }
    __syncthreads();
    const int j0 = jb + jsub * 16;
    f32x4 acc = {0.f,0.f,0.f,0.f};
    const unsigned short* bbase = &qlds[(jsub * 16 + col) * LSTR + kg * 8];
    #pragma unroll
    for (int kb = 0; kb < 16; ++kb){
      short8_t bfrag = *reinterpret_cast<const short8_t*>(bbase + kb * 32);
      acc = __builtin_amdgcn_mfma_f32_16x16x32_bf16(afrag[kb], bfrag, acc, 0, 0, 0);
    }
    const int j = j0 + col;
    if (j < M){
      const int dt = j - iw - kg * 4;
      #pragma unroll
      for (int r = 0; r < 4; ++r){
        float lg = acc[r];
        es[r]  += expf(lg);
        lsm[r] += lg;
        int d = dt - r; int ad = d < 0 ? -d : d;
        if (ad <= RADIUS) bg[r] += gtab[ad] * lg;
      }
    }
  }
  #pragma unroll
  for (int m = 1; m < 16; m <<= 1){
    #pragma unroll
    for (int r = 0; r < 4; ++r){
      es[r]  += __shfl_xor(es[r],  m, 64);
      lsm[r] += __shfl_xor(lsm[r], m, 64);
      bg[r]  += __shfl_xor(bg[r],  m, 64);
    }
  }
  if (col == 0){
    #pragma unroll
    for (int r = 0; r < 4; ++r){
      int lrow = isub * 16 + kg * 4 + r;
      partials[jsub][lrow][0] = es[r];
      partials[jsub][lrow][1] = lsm[r];
      partials[jsub][lrow][2] = bg[r];
    }
  }
  __syncthreads();
  if (tid < TI){
    int i = i0 + tid;
    if (i < M){
      float esf = partials[0][tid][0] + partials[1][tid][0];
      float lsf = partials[0][tid][1] + partials[1][tid][1];
      float bgf = partials[0][tid][2] + partials[1][tid][2];
      int dlo = (-RADIUS < -i) ? -i : -RADIUS;
      int dhi = (RADIUS > M - 1 - i) ? (M - 1 - i) : RADIUS;
      float Zt = (float)M, U = 0.f;
      for (int d = dlo; d <= dhi; ++d){
        float uu = CF * expf(-(float)(d * d) * 0.125f);
        float eu = expf(uu);
        Zt += eu - 1.0f;
        U  += uu * eu;
      }
      row_sums[(size_t)b * LL + i] = (U - lsf - bgf) / Zt + logf(esf / Zt);
    }
  }
}

__global__ void fb_finalize(const float* __restrict__ row_sums,
                            const int* __restrict__ mcnt, float* __restrict__ out){
  __shared__ float red[256];
  float acc = 0.f;
  for (int b = 0; b < BB; ++b){
    int M = mcnt[b];
    float s = 0.f;
    for (int i = threadIdx.x; i < M; i += 256) s += row_sums[(size_t)b * LL + i];
    red[threadIdx.x] = s; __syncthreads();
    for (int k = 128; k; k >>= 1){
      if (threadIdx.x < k) red[threadIdx.x] += red[threadIdx.x + k];
      __syncthreads();
    }
    if (threadIdx.x == 0) acc += red[0] / (float)M;
    __syncthreads();
  }
  if (threadIdx.x == 0) out[0] = acc / (float)BB;
}

// ================================ launch ================================

extern "C" void kernel_launch(void* const* d_in, const int* in_sizes, int n_in,
                              void* d_out, int out_size, void* d_ws, size_t ws_size,
                              hipStream_t stream) {
  const float* embs = (const float*)d_in[0];
  const float* clip = (const float*)d_in[1];
  const int*   mask = (const int*)d_in[2];
  float* out = (float*)d_out;

  const size_t REQ = (size_t)2 * BL * DD * sizeof(unsigned short)   // p_bf + q_bf
                   + (size_t)BB * LL * 16 * sizeof(float)           // partials (4 slices)
                   + 64 * sizeof(float);                            // psum + mcnt
  if (ws_size >= REQ){
    unsigned short* p_bf = (unsigned short*)d_ws;
    unsigned short* q_bf = p_bf + (size_t)BL * DD;
    float* part = (float*)(q_bf + (size_t)BL * DD);
    float* psum = part + (size_t)BB * LL * 16;
    int*   mcnt = (int*)(psum + 16);

    mcount_kernel<<<dim3(BB), 256, 0, stream>>>(mask, mcnt);
    precvt<<<dim3(2 * BL / 4), 256, 0, stream>>>(embs, clip, mcnt, p_bf, q_bf);
    gram4<<<dim3(1024), 256, 0, stream>>>(p_bf, q_bf, mcnt, part);
    finalize1<<<dim3(BB), 256, 0, stream>>>(part, mcnt, psum);
    finalize2<<<1, 64, 0, stream>>>(psum, out);
  } else {
    float* ws   = (float*)d_ws;
    float* invq = ws;
    int*   mcnt = (int*)(ws + BL);
    float* rows = ws + BL + 16;
    fb_qnorm<<<dim3(BL), 128, 0, stream>>>(clip, invq);
    mcount_kernel<<<dim3(BB), 256, 0, stream>>>(mask, mcnt);
    fb_main<<<dim3(LL / TI, BB), 256, 0, stream>>>(embs, clip, invq, mcnt, rows);
    fb_finalize<<<1, 256, 0, stream>>>(rows, mcnt, out);
  }
}